// Round 2
// baseline (545.238 us; speedup 1.0000x reference)
//
#include <hip/hip_runtime.h>
#include <cstdint>
#include <cstddef>

#define NN 20000   // nodes
#define NE 320000  // edges
#define NB 4       // batch
#define NF 16      // f_in
#define NH 64      // hidden
#define NP 12      // periods
#define FP (NF*NP) // 192 features per node row

// ---------------- CSR construction ----------------

__global__ __launch_bounds__(256) void k_init(float* deg, int* counts, int* cursor) {
    int i = blockIdx.x * 256 + threadIdx.x;
    if (i < NN) { deg[i] = 1.0f; counts[i] = 0; cursor[i] = 0; } // deg starts at 1.0 (self loop)
}

// NOTE: harness passes integer inputs as int32 — edge_index is const int* [2][NE]
__global__ __launch_bounds__(256) void k_degcount(const int* __restrict__ ei,
                                                  const float* __restrict__ ew,
                                                  float* deg, int* counts) {
    int e = blockIdx.x * 256 + threadIdx.x;
    if (e < NE) {
        int dst = ei[NE + e];
        atomicAdd(&deg[dst], ew[e]);
        atomicAdd(&counts[dst], 1);
    }
}

__global__ __launch_bounds__(256) void k_dinv(const float* __restrict__ deg, float* dinv) {
    int i = blockIdx.x * 256 + threadIdx.x;
    if (i < NN) { float d = deg[i]; dinv[i] = d > 0.f ? rsqrtf(d) : 0.f; }
}

// single-block exclusive scan of counts -> offsets[NN+1]
__global__ __launch_bounds__(1024) void k_scan(const int* __restrict__ counts, int* __restrict__ offsets) {
    __shared__ int sums[1024];
    int t = threadIdx.x;
    const int PER = (NN + 1023) / 1024; // 20
    int start = t * PER;
    int end   = start + PER; if (end > NN) end = NN;
    int s = 0;
    for (int i = start; i < end && start < NN; ++i) s += counts[i];
    if (start >= NN) s = 0;
    sums[t] = s;
    __syncthreads();
    // Hillis-Steele inclusive scan
    for (int off = 1; off < 1024; off <<= 1) {
        int v = (t >= off) ? sums[t - off] : 0;
        __syncthreads();
        sums[t] += v;
        __syncthreads();
    }
    int run = (t == 0) ? 0 : sums[t - 1];
    for (int i = start; i < end && start < NN; ++i) { offsets[i] = run; run += counts[i]; }
    if (t == 1023) offsets[NN] = sums[1023]; // == NE
}

__global__ __launch_bounds__(256) void k_fill(const int* __restrict__ ei,
                                              const float* __restrict__ ew,
                                              const float* __restrict__ dinv,
                                              const int* __restrict__ offsets,
                                              int* cursor, int* src_list, float* norm_list) {
    int e = blockIdx.x * 256 + threadIdx.x;
    if (e < NE) {
        int s = ei[e];
        int d = ei[NE + e];
        float nm = dinv[s] * ew[e] * dinv[d];
        int pos = atomicAdd(&cursor[d], 1);
        int idx = offsets[d] + pos;
        src_list[idx]  = s;
        norm_list[idx] = nm;
    }
}

// ---------------- effective weight folding ----------------
// H0 == 0 in the reference scan (carry is the accumulator, hidden state is
// always the zero closure constant), so:
//   Z  = sigmoid(a @ (Wg_z @ Wl_z[:64]) + (bg_z @ Wl_z[:64] + bl_z))
//   Ht = tanh  (a @ (Wg_h @ Wl_h[:64]) + (bg_h @ Wl_h[:64] + bl_h))
//   Hn = (1-Z)*Ht          (R path multiplies H0=0 -> dead)
__global__ __launch_bounds__(1024) void k_weights(
        const float* __restrict__ Wg_z, const float* __restrict__ bg_z,
        const float* __restrict__ Wg_h, const float* __restrict__ bg_h,
        const float* __restrict__ Wl_z, const float* __restrict__ bl_z,
        const float* __restrict__ Wl_h, const float* __restrict__ bl_h,
        const float* __restrict__ att,
        float* Wz_eff, float* Wh_eff, float* bz_eff, float* bh_eff, float* probs) {
    int t = threadIdx.x;         // 0..1023 = f*64 + j
    int f = t >> 6, j = t & 63;
    float sz = 0.f, sh = 0.f;
    for (int k = 0; k < NH; ++k) {
        sz += Wg_z[f * NH + k] * Wl_z[k * NH + j];
        sh += Wg_h[f * NH + k] * Wl_h[k * NH + j];
    }
    Wz_eff[t] = sz;
    Wh_eff[t] = sh;
    if (t < NH) {
        float bz = bl_z[t], bh = bl_h[t];
        for (int k = 0; k < NH; ++k) {
            bz += bg_z[k] * Wl_z[k * NH + t];
            bh += bg_h[k] * Wl_h[k * NH + t];
        }
        bz_eff[t] = bz;
        bh_eff[t] = bh;
    }
    if (t == 0) {
        float m = att[0];
        for (int p = 1; p < NP; ++p) m = fmaxf(m, att[p]);
        float s = 0.f, e_[NP];
        for (int p = 0; p < NP; ++p) { e_[p] = expf(att[p] - m); s += e_[p]; }
        for (int p = 0; p < NP; ++p) probs[p] = e_[p] / s;
    }
}

// ---------------- fused aggregate + GRU + attention + output ----------------
// 1 block per node; wave w (of 4) handles batch w; lane = hidden dim (64)
__global__ __launch_bounds__(256) void k_main(
        const float* __restrict__ x,
        const int* __restrict__ offsets, const int* __restrict__ src_list,
        const float* __restrict__ norm_list, const float* __restrict__ dinv,
        const float* __restrict__ Wz_eff, const float* __restrict__ Wh_eff,
        const float* __restrict__ bz_eff, const float* __restrict__ bh_eff,
        const float* __restrict__ probs, const float* __restrict__ W_out,
        const float* __restrict__ b_out, float* __restrict__ out) {
    __shared__ float a_lds[NB][FP];
    int n = blockIdx.x;
    int b = threadIdx.x >> 6;
    int lane = threadIdx.x & 63;

    float di = dinv[n];
    float sw = di * di;            // self-loop norm
    size_t xb = ((size_t)b * NN + n) * FP;
    float a0 = sw * x[xb + lane];
    float a1 = sw * x[xb + 64 + lane];
    float a2 = sw * x[xb + 128 + lane];

    int beg = offsets[n], end = offsets[n + 1];
    for (int e = beg; e < end; ++e) {
        int s = src_list[e];
        float nm = norm_list[e];
        size_t sb = ((size_t)b * NN + s) * FP;
        a0 += nm * x[sb + lane];
        a1 += nm * x[sb + 64 + lane];
        a2 += nm * x[sb + 128 + lane];
    }
    a_lds[b][lane]       = a0;
    a_lds[b][64 + lane]  = a1;
    a_lds[b][128 + lane] = a2;
    __syncthreads();

    float Wz[NF], Wh[NF];
#pragma unroll
    for (int f = 0; f < NF; ++f) {
        Wz[f] = Wz_eff[f * NH + lane];
        Wh[f] = Wh_eff[f * NH + lane];
    }
    float bz = bz_eff[lane], bh = bh_eff[lane];

    float hacc = 0.f;
#pragma unroll
    for (int p = 0; p < NP; ++p) {
        float z = bz, h = bh;
#pragma unroll
        for (int f = 0; f < NF; ++f) {
            float a = a_lds[b][f * NP + p];   // uniform address -> LDS broadcast
            z += a * Wz[f];
            h += a * Wh[f];
        }
        float zs = 1.f / (1.f + expf(-z));
        hacc += probs[p] * (1.f - zs) * tanhf(h);
    }

    float r = fmaxf(hacc, 0.f);
    float o[NP];
#pragma unroll
    for (int k = 0; k < NP; ++k) o[k] = r * W_out[lane * NP + k];
#pragma unroll
    for (int off = 32; off > 0; off >>= 1) {
#pragma unroll
        for (int k = 0; k < NP; ++k) o[k] += __shfl_xor(o[k], off, 64);
    }
    if (lane == 0) {
        size_t ob = ((size_t)b * NN + n) * NP;
#pragma unroll
        for (int k = 0; k < NP; ++k) out[ob + k] = o[k] + b_out[k];
    }
}

// ---------------- launch ----------------

extern "C" void kernel_launch(void* const* d_in, const int* in_sizes, int n_in,
                              void* d_out, int out_size, void* d_ws, size_t ws_size,
                              hipStream_t stream) {
    const float* x     = (const float*)d_in[0];
    const int*   ei    = (const int*)d_in[1];    // int32 per harness (shape [2][NE])
    const float* ew    = (const float*)d_in[2];
    const float* Wg_z  = (const float*)d_in[3];
    const float* bg_z  = (const float*)d_in[4];
    // d_in[5], d_in[6]: Wg_r/bg_r — dead (H0==0)
    const float* Wg_h  = (const float*)d_in[7];
    const float* bg_h  = (const float*)d_in[8];
    const float* Wl_z  = (const float*)d_in[9];
    const float* bl_z  = (const float*)d_in[10];
    // d_in[11], d_in[12]: Wl_r/bl_r — dead
    const float* Wl_h  = (const float*)d_in[13];
    const float* bl_h  = (const float*)d_in[14];
    const float* att   = (const float*)d_in[15];
    const float* W_out = (const float*)d_in[16];
    const float* b_out = (const float*)d_in[17];
    float*       out   = (float*)d_out;

    char* p = (char*)d_ws;
    auto alloc = [&](size_t bytes) -> void* {
        void* r = (void*)p;
        p += (bytes + 255) & ~(size_t)255;
        return r;
    };
    float* deg       = (float*)alloc(NN * 4);
    float* dinv      = (float*)alloc(NN * 4);
    int*   counts    = (int*)  alloc(NN * 4);
    int*   cursor    = (int*)  alloc(NN * 4);
    int*   offsets   = (int*)  alloc((NN + 1) * 4);
    int*   src_list  = (int*)  alloc(NE * 4);
    float* norm_list = (float*)alloc(NE * 4);
    float* Wz_eff    = (float*)alloc(NF * NH * 4);
    float* Wh_eff    = (float*)alloc(NF * NH * 4);
    float* bz_eff    = (float*)alloc(NH * 4);
    float* bh_eff    = (float*)alloc(NH * 4);
    float* probs     = (float*)alloc(16 * 4);

    k_init    <<<(NN + 255) / 256, 256, 0, stream>>>(deg, counts, cursor);
    k_degcount<<<(NE + 255) / 256, 256, 0, stream>>>(ei, ew, deg, counts);
    k_dinv    <<<(NN + 255) / 256, 256, 0, stream>>>(deg, dinv);
    k_scan    <<<1, 1024, 0, stream>>>(counts, offsets);
    k_fill    <<<(NE + 255) / 256, 256, 0, stream>>>(ei, ew, dinv, offsets, cursor, src_list, norm_list);
    k_weights <<<1, 1024, 0, stream>>>(Wg_z, bg_z, Wg_h, bg_h, Wl_z, bl_z, Wl_h, bl_h, att,
                                       Wz_eff, Wh_eff, bz_eff, bh_eff, probs);
    k_main    <<<NN, 256, 0, stream>>>(x, offsets, src_list, norm_list, dinv,
                                       Wz_eff, Wh_eff, bz_eff, bh_eff, probs, W_out, b_out, out);
}